// Round 6
// baseline (169.304 us; speedup 1.0000x reference)
//
#include <hip/hip_runtime.h>

#define B 4
#define C 256
#define CQ 32
#define NN 13824   // 24^3
#define MM 1728    // 12^3
#define MS 12

typedef __attribute__((ext_vector_type(8))) short short8;    // 8 bf16 = 4 VGPRs
typedef __attribute__((ext_vector_type(4))) float float4_;   // 16x16 MFMA C/D
typedef __attribute__((ext_vector_type(16))) float floatx16; // 32x32 MFMA C/D

static __device__ inline unsigned rne_bf16(float x) {
  unsigned u = __float_as_uint(x);
  u += 0x7FFFu + ((u >> 16) & 1u);   // round-to-nearest-even bf16
  return u >> 16;
}

// HW packed fp32->bf16 (RNE, bit-identical to rne_bf16 pair). 1 instr vs ~6.
static __device__ inline unsigned cvtpk(float lo, float hi) {
  unsigned r;
  asm("v_cvt_pk_bf16_f32 %0, %1, %2" : "=v"(r) : "v"(lo), "v"(hi));
  return r;
}

#define LOG2E 1.4426950408889634f
#define EXPOFS 43.28085122666891f   // 30 * log2(e)

// ---------------------------------------------------------------------------
// K1: projections as MFMA GEMM.  [96,256] x [256, NN] per batch.
// r11: (a) 864 blocks x 128 thr (n-tile 64): CU imbalance 2:1 -> 4:3 and
//      3.4 blocks/CU resident (LDS 20.5 KB). Per-wave work unchanged.
//      (b) wcvt kernel ELIMINATED: W read as fp32 here and packed to the
//      A-frag LDS layout with v_cvt_pk_bf16_f32 (bit-identical RNE).
// ---------------------------------------------------------------------------
#define LOADX(SET, CH)                                                        \
  do {                                                                        \
    const float* xp = xbase4 + (size_t)((CH)*32 + kg * 4) * NN;               \
    _Pragma("unroll") for (int j = 0; j < 4; ++j)                             \
        vx4[SET][j] = *reinterpret_cast<const float4*>(xp + (size_t)j * NN);  \
  } while (0)

#define PACKX(SET, BUF)                                                       \
  do {                                                                        \
    _Pragma("unroll") for (int i = 0; i < 4; ++i) {                           \
      *reinterpret_cast<uint2*>(&xls[BUF][kg >> 1][nq * 4 + i][(kg & 1) * 4]) = \
          make_uint2(cvtpk(vx4[SET][0][i], vx4[SET][1][i]),                   \
                     cvtpk(vx4[SET][2][i], vx4[SET][3][i]));                  \
    }                                                                         \
  } while (0)

#define LOADW(CH)                                                             \
  do {                                                                        \
    _Pragma("unroll") for (int i = 0; i < 3; ++i) {                           \
      wv[i][0] = *reinterpret_cast<const float4*>(wrow[i] + (CH)*32);         \
      wv[i][1] = *reinterpret_cast<const float4*>(wrow[i] + (CH)*32 + 4);     \
    }                                                                         \
  } while (0)

#define STOREW(BUF)                                                           \
  do {                                                                        \
    uint4* dst = reinterpret_cast<uint4*>(&wls[BUF][0][0][0]);                \
    _Pragma("unroll") for (int i = 0; i < 3; ++i)                             \
      dst[i * 128 + t] =                                                      \
          make_uint4(cvtpk(wv[i][0].x, wv[i][0].y),                           \
                     cvtpk(wv[i][0].z, wv[i][0].w),                           \
                     cvtpk(wv[i][1].x, wv[i][1].y),                           \
                     cvtpk(wv[i][1].z, wv[i][1].w));                          \
  } while (0)

#define COMPUTE(BUF)                                                          \
  do {                                                                        \
    _Pragma("unroll") for (int ks = 0; ks < 2; ++ks) {                        \
      const int kq = ks * 2 + hi;                                             \
      const short8 bfr =                                                      \
          *reinterpret_cast<const short8*>(&xls[BUF][kq][w * 32 + col][0]);   \
      const short8 a0 = *reinterpret_cast<const short8*>(&wls[BUF][kq][col][0]);      \
      const short8 a1 = *reinterpret_cast<const short8*>(&wls[BUF][kq][32 + col][0]); \
      const short8 a2 = *reinterpret_cast<const short8*>(&wls[BUF][kq][64 + col][0]); \
      accf = __builtin_amdgcn_mfma_f32_32x32x16_bf16(a0, bfr, accf, 0, 0, 0); \
      accg = __builtin_amdgcn_mfma_f32_32x32x16_bf16(a1, bfr, accg, 0, 0, 0); \
      acch = __builtin_amdgcn_mfma_f32_32x32x16_bf16(a2, bfr, acch, 0, 0, 0); \
    }                                                                         \
  } while (0)

__global__ __launch_bounds__(128) void proj_mfma(
    const float* __restrict__ x, const float* __restrict__ Wf,
    const float* __restrict__ Wg, const float* __restrict__ Wh,
    unsigned short* __restrict__ f16, unsigned short* __restrict__ g16,
    unsigned short* __restrict__ h16) {
  __shared__ __align__(16) unsigned short xls[2][4][64][8];   // 8 KB
  __shared__ __align__(16) unsigned short wls[2][4][96][8];   // 12 KB
  const int blk = blockIdx.x;                     // 864
  const int b = blk / 216;
  const int n0 = (blk - b * 216) * 64;
  const int t = threadIdx.x;                      // 128 threads = 2 waves
  const int w = t >> 6, lane = t & 63;
  const int col = lane & 31, hi = lane >> 5;
  const int nq = t & 15, kg = t >> 4;             // staging: n-quad, k-quad

  // W fp32 row pointers for this thread's 3 uint4 staging slots.
  // slot u = i*128+t: kq = u/96, m = u%96 (m: 0-31 f | 32-63 g | 64-95 h);
  // slot holds W[m][ch*32 + kq*8 .. +8].
  const float* wrow[3];
#pragma unroll
  for (int i = 0; i < 3; ++i) {
    const int u = i * 128 + t;
    const int kq = u / 96, m = u - kq * 96;
    const float* base = (m < 32) ? (Wf + m * C)
                      : (m < 64) ? (Wg + (m - 32) * C)
                                 : (Wh + (m - 64) * C);
    wrow[i] = base + kq * 8;
  }

  floatx16 accf = {0}, accg = {0}, acch = {0};
  const float* xbase4 = x + ((size_t)b * C) * NN + n0 + nq * 4;
  float4 vx4[3][4];         // 3 in-flight register chunk sets (static idx)
  float4 wv[3][2];

  // prologue: issue chunks 0,1,2 + W0; pack chunk0 -> LDS[0]
  LOADX(0, 0);
  LOADX(1, 1);
  LOADX(2, 2);
  LOADW(0);
  PACKX(0, 0);
  STOREW(0);
  __syncthreads();

#pragma unroll
  for (int ch = 0; ch < 8; ++ch) {
    const int buf = ch & 1;
    if (ch + 1 < 8) LOADW(ch + 1);                // W next chunk -> regs
    if (ch + 3 < 8) LOADX((ch + 3) % 3, ch + 3);  // x chunk+3 -> ring set
    COMPUTE(buf);
    if (ch + 1 < 8) {                             // write-late: ch+1 -> LDS
      PACKX((ch + 1) % 3, buf ^ 1);
      STOREW(buf ^ 1);
      __syncthreads();
    }
  }

  // ---- epilogue. D layout: col=lane&31 (x n-index), row=(r&3)+8*(r>>2)+4*hi.
  const int n = n0 + w * 32 + col;
  {  // f: bf16 [b][n][c], pack row-pairs -> 8 dword stores
    unsigned short* fp = f16 + ((size_t)b * NN + n) * 32 + hi * 4;
#pragma unroll
    for (int rp = 0; rp < 8; ++rp) {
      const int m = (rp & 1) * 2 + 8 * (rp >> 1);   // 0,2,8,10,16,18,24,26
      *reinterpret_cast<unsigned*>(fp + m) = cvtpk(accf[rp * 2], accf[rp * 2 + 1]);
    }
  }
  unsigned short* gp = g16 + (size_t)b * CQ * NN + n;
  unsigned short* hp = h16 + (size_t)b * CQ * NN + n;
#pragma unroll
  for (int r = 0; r < 16; ++r) {
    const int c = (r & 3) + 8 * (r >> 2) + 4 * hi;
    gp[(size_t)c * NN] = (unsigned short)rne_bf16(accg[r]);
    hp[(size_t)c * NN] = (unsigned short)rne_bf16(acch[r]);
  }
}

// ---------------------------------------------------------------------------
// K2: 2x2x2 maxpool, bf16 in -> bf16 out. (unchanged)
// ---------------------------------------------------------------------------
__global__ __launch_bounds__(256) void pool_kernel(
    const unsigned short* __restrict__ g16, const unsigned short* __restrict__ h16,
    unsigned short* __restrict__ gt16, unsigned short* __restrict__ ht16) {
  int i = blockIdx.x * 256 + threadIdx.x;            // [0, B*CQ*MM)
  const int m = i % MM;
  const int rest = i / MM;
  const int c = rest & 31;
  const int b = rest >> 5;
  const int wq = m % MS;
  const int hq = (m / MS) % MS;
  const int dq = m / (MS * MS);
  const size_t base = ((size_t)b * CQ + c) * NN +
                      (2 * dq) * 576 + (2 * hq) * 24 + (2 * wq);
  auto mx2 = [](unsigned u) {
    return fmaxf(__uint_as_float(u << 16), __uint_as_float(u & 0xFFFF0000u));
  };
  const unsigned short* pg = g16 + base;
  const unsigned short* ph = h16 + base;
  float vg = fmaxf(fmaxf(mx2(*(const unsigned*)(pg)),
                         mx2(*(const unsigned*)(pg + 24))),
                   fmaxf(mx2(*(const unsigned*)(pg + 576)),
                         mx2(*(const unsigned*)(pg + 600))));
  float vh = fmaxf(fmaxf(mx2(*(const unsigned*)(ph)),
                         mx2(*(const unsigned*)(ph + 24))),
                   fmaxf(mx2(*(const unsigned*)(ph + 576)),
                         mx2(*(const unsigned*)(ph + 600))));
  gt16[((size_t)b * MM + m) * 32 + c] = (unsigned short)(__float_as_uint(vg) >> 16);
  ht16[((size_t)b * 32 + c) * MM + m] = (unsigned short)(__float_as_uint(vh) >> 16);
}

// ---------------------------------------------------------------------------
// K3: MFMA flash attention + MFMA out-projection/residual.
// r11: main loop IDENTICAL to r10 (verified 54.7us). Epilogue now builds the
// double-bf16 Wv A-frags from fp32 in-register (hi=rne(v), lo=rne(v-hi) —
// bit-identical to the old wcvt precompute), dropping the Whv/Wlv buffers.
// ---------------------------------------------------------------------------
static __device__ inline void dbl_frag(const float* __restrict__ p,
                                       short8& hi8, short8& lo8) {
  const float4 v0 = *reinterpret_cast<const float4*>(p);
  const float4 v1 = *reinterpret_cast<const float4*>(p + 4);
  uint4 h, l;
  h.x = cvtpk(v0.x, v0.y);
  h.y = cvtpk(v0.z, v0.w);
  h.z = cvtpk(v1.x, v1.y);
  h.w = cvtpk(v1.z, v1.w);
  l.x = cvtpk(v0.x - __uint_as_float(h.x << 16),
              v0.y - __uint_as_float(h.x & 0xFFFF0000u));
  l.y = cvtpk(v0.z - __uint_as_float(h.y << 16),
              v0.w - __uint_as_float(h.y & 0xFFFF0000u));
  l.z = cvtpk(v1.x - __uint_as_float(h.z << 16),
              v1.y - __uint_as_float(h.z & 0xFFFF0000u));
  l.w = cvtpk(v1.z - __uint_as_float(h.w << 16),
              v1.w - __uint_as_float(h.w & 0xFFFF0000u));
  hi8 = *reinterpret_cast<short8*>(&h);
  lo8 = *reinterpret_cast<short8*>(&l);
}

__global__ __launch_bounds__(256, 4) void attn_kernel(
    const unsigned short* __restrict__ f16, const unsigned short* __restrict__ gt,
    const unsigned short* __restrict__ ht, const float* __restrict__ x,
    const float* __restrict__ Wv, const float* __restrict__ gamma,
    float* __restrict__ out) {
  __shared__ __align__(16) unsigned short sm[16896];
  const int blk = blockIdx.x;               // 864
  const int b = blk / 216;
  const int n0 = (blk - b * 216) * 64;
  const int t = threadIdx.x;
  const int w = t >> 6, L = t & 63, Q = L >> 4, col = L & 15;

  unsigned short* fls = sm;
  unsigned short* g0 = sm + 2560;
  unsigned short* g1 = sm + 5120;
  unsigned short* h0 = sm + 7680;
  unsigned short* h1 = sm + 9984;
  unsigned short* Pls = sm + 12288 + w * 1152;

  {
    const unsigned short* fsrc = f16 + ((size_t)(b * NN + n0)) * 32;
    *reinterpret_cast<uint4*>(fls + (t >> 2) * 40 + (t & 3) * 8) =
        *reinterpret_cast<const uint4*>(fsrc + t * 8);
  }
  const unsigned short* gsrc = gt + (size_t)b * MM * 32;
  const unsigned short* hsrc = ht + (size_t)b * 32 * MM;
  const int gk = t >> 2, gseg = t & 3;
  const int hc = t >> 3, hseg = t & 7;
  *reinterpret_cast<uint4*>(g0 + gk * 40 + gseg * 8) =
      *reinterpret_cast<const uint4*>(gsrc + gk * 32 + gseg * 8);
  *reinterpret_cast<uint4*>(h0 + hc * 72 + hseg * 8) =
      *reinterpret_cast<const uint4*>(hsrc + (size_t)hc * MM + hseg * 8);
  __syncthreads();

  const short8 fB = *reinterpret_cast<const short8*>(fls + (w * 16 + col) * 40 + Q * 8);

  float4_ acc0 = {0.f, 0.f, 0.f, 0.f}, acc1 = {0.f, 0.f, 0.f, 0.f};
  float l0 = 0.f, l1 = 0.f;

  for (int ch = 0; ch < 27; ++ch) {
    unsigned short* gcur = (ch & 1) ? g1 : g0;
    unsigned short* hcur = (ch & 1) ? h1 : h0;
    uint4 gnx, hnx;
    if (ch < 26) {
      const int k0 = (ch + 1) * 64;
      gnx = *reinterpret_cast<const uint4*>(gsrc + (size_t)(k0 + gk) * 32 + gseg * 8);
      hnx = *reinterpret_cast<const uint4*>(hsrc + (size_t)hc * MM + k0 + hseg * 8);
    }
    float4_ sc[4];
    __builtin_amdgcn_s_setprio(1);
#pragma unroll
    for (int T = 0; T < 4; ++T) {
      const short8 gA =
          *reinterpret_cast<const short8*>(gcur + (T * 16 + col) * 40 + Q * 8);
      float4_ z = {0.f, 0.f, 0.f, 0.f};
      sc[T] = __builtin_amdgcn_mfma_f32_16x16x32_bf16(gA, fB, z, 0, 0, 0);
    }
    __builtin_amdgcn_s_setprio(0);
#pragma unroll
    for (int T = 0; T < 4; ++T) {
      const float p0 = exp2f(fmaf(sc[T][0], LOG2E, -EXPOFS));
      const float p1 = exp2f(fmaf(sc[T][1], LOG2E, -EXPOFS));
      const float p2 = exp2f(fmaf(sc[T][2], LOG2E, -EXPOFS));
      const float p3 = exp2f(fmaf(sc[T][3], LOG2E, -EXPOFS));
      l0 += p0 + p1;
      l1 += p2 + p3;
      unsigned short* pw = Pls + col * 72 + T * 16 + Q * 4;
      *reinterpret_cast<uint2*>(pw) =
          make_uint2(cvtpk(p0, p1), cvtpk(p2, p3));
    }
#pragma unroll
    for (int ks = 0; ks < 2; ++ks) {
      const short8 pA =
          *reinterpret_cast<const short8*>(Pls + col * 72 + ks * 32 + Q * 8);
      const short8 hB0 =
          *reinterpret_cast<const short8*>(hcur + col * 72 + ks * 32 + Q * 8);
      const short8 hB1 =
          *reinterpret_cast<const short8*>(hcur + (16 + col) * 72 + ks * 32 + Q * 8);
      __builtin_amdgcn_s_setprio(1);
      acc0 = __builtin_amdgcn_mfma_f32_16x16x32_bf16(pA, hB0, acc0, 0, 0, 0);
      acc1 = __builtin_amdgcn_mfma_f32_16x16x32_bf16(pA, hB1, acc1, 0, 0, 0);
      __builtin_amdgcn_s_setprio(0);
    }
    if (ch < 26) {
      unsigned short* gnb = (ch & 1) ? g0 : g1;
      unsigned short* hnb = (ch & 1) ? h0 : h1;
      *reinterpret_cast<uint4*>(gnb + gk * 40 + gseg * 8) = gnx;
      *reinterpret_cast<uint4*>(hnb + hc * 72 + hseg * 8) = hnx;
    }
    __syncthreads();
  }

  // ---- softmax denominator + park o in LDS (stride 33: conflict-free).
  float l = l0 + l1;
  l += __shfl_xor(l, 16);
  l += __shfl_xor(l, 32);
  float* ols = reinterpret_cast<float*>(sm);   // [64][33] fp32 = 8448 B
#pragma unroll
  for (int r = 0; r < 4; ++r) {
    const float linv = 1.f / __shfl(l, Q * 4 + r);
    const int nl = w * 16 + Q * 4 + r;
    ols[nl * 33 + col] = acc0[r] * linv;
    ols[nl * 33 + 16 + col] = acc1[r] * linv;
  }
  __syncthreads();

  // ---- MFMA out-projection: D[256 c][64 n] = (Wv_hi+Wv_lo) @ o^T, + gamma/x.
  const int colA = L & 31, hiA = L >> 5;
  const float gm = gamma[0];
  short8 Bf[2][2];
#pragma unroll
  for (int nt = 0; nt < 2; ++nt) {
#pragma unroll
    for (int ks = 0; ks < 2; ++ks) {
      const float* p = &ols[(nt * 32 + colA) * 33 + ks * 16 + hiA * 8];
      uint4 uu;
      uu.x = cvtpk(p[0], p[1]);
      uu.y = cvtpk(p[2], p[3]);
      uu.z = cvtpk(p[4], p[5]);
      uu.w = cvtpk(p[6], p[7]);
      Bf[nt][ks] = *reinterpret_cast<short8*>(&uu);
    }
  }
#pragma unroll
  for (int tt = 0; tt < 2; ++tt) {
    const int ct = w + tt * 4;                   // c-tile 0..7
    const int ca = ct * 32 + colA;               // A row = out channel
    short8 Ah0, Al0, Ah1, Al1;
    dbl_frag(Wv + ca * 32 + hiA * 8, Ah0, Al0);
    dbl_frag(Wv + ca * 32 + 16 + hiA * 8, Ah1, Al1);
    floatx16 ac0 = {0}, ac1 = {0};
    __builtin_amdgcn_s_setprio(1);
    ac0 = __builtin_amdgcn_mfma_f32_32x32x16_bf16(Ah0, Bf[0][0], ac0, 0, 0, 0);
    ac0 = __builtin_amdgcn_mfma_f32_32x32x16_bf16(Ah1, Bf[0][1], ac0, 0, 0, 0);
    ac0 = __builtin_amdgcn_mfma_f32_32x32x16_bf16(Al0, Bf[0][0], ac0, 0, 0, 0);
    ac0 = __builtin_amdgcn_mfma_f32_32x32x16_bf16(Al1, Bf[0][1], ac0, 0, 0, 0);
    ac1 = __builtin_amdgcn_mfma_f32_32x32x16_bf16(Ah0, Bf[1][0], ac1, 0, 0, 0);
    ac1 = __builtin_amdgcn_mfma_f32_32x32x16_bf16(Ah1, Bf[1][1], ac1, 0, 0, 0);
    ac1 = __builtin_amdgcn_mfma_f32_32x32x16_bf16(Al0, Bf[1][0], ac1, 0, 0, 0);
    ac1 = __builtin_amdgcn_mfma_f32_32x32x16_bf16(Al1, Bf[1][1], ac1, 0, 0, 0);
    __builtin_amdgcn_s_setprio(0);
#pragma unroll
    for (int nt = 0; nt < 2; ++nt) {
      const floatx16 av = nt ? ac1 : ac0;
      const int n = n0 + nt * 32 + colA;
      const float* xp = x + ((size_t)b * C + ct * 32 + 4 * hiA) * NN + n;
      float* op = out + ((size_t)b * C + ct * 32 + 4 * hiA) * NN + n;
      float xv[16];
#pragma unroll
      for (int r = 0; r < 16; ++r)
        xv[r] = xp[(size_t)((r & 3) + 8 * (r >> 2)) * NN];
#pragma unroll
      for (int r = 0; r < 16; ++r)
        op[(size_t)((r & 3) + 8 * (r >> 2)) * NN] = gm * av[r] + xv[r];
    }
  }
}

// ---------------------------------------------------------------------------
// Workspace layout (float units):
//   f16  @ 0        (884736 fl = [b][n][32] bf16)
//   g16  @ 884736   (884736 fl = [b][c][n] bf16)
//   h16  @ 1769472  (884736)
//   gt16 @ 4423680  (110592 fl = [b][m][c] bf16)
//   ht16 @ 4534272  (110592 fl = [b][c][m] bf16)
// (wcvt kernel + W16c/Whv/Wlv regions removed in r11.)
// ---------------------------------------------------------------------------
extern "C" void kernel_launch(void* const* d_in, const int* in_sizes, int n_in,
                              void* d_out, int out_size, void* d_ws, size_t ws_size,
                              hipStream_t stream) {
  const float* x     = (const float*)d_in[0];
  const float* Wf    = (const float*)d_in[1];
  const float* Wg    = (const float*)d_in[2];
  const float* Wh    = (const float*)d_in[3];
  const float* Wv    = (const float*)d_in[4];
  const float* gamma = (const float*)d_in[5];
  float* out = (float*)d_out;
  float* ws = (float*)d_ws;

  unsigned short* f16  = (unsigned short*)ws;
  unsigned short* g16  = (unsigned short*)(ws + 884736);
  unsigned short* h16  = (unsigned short*)(ws + 1769472);
  unsigned short* gt16 = (unsigned short*)(ws + 4423680);
  unsigned short* ht16 = (unsigned short*)(ws + 4534272);

  proj_mfma<<<B * 216, 128, 0, stream>>>(x, Wf, Wg, Wh, f16, g16, h16);
  pool_kernel<<<(B * CQ * MM) / 256, 256, 0, stream>>>(g16, h16, gt16, ht16);
  attn_kernel<<<B * (NN / 64), 256, 0, stream>>>(f16, gt16, ht16, x, Wv,
                                                 gamma, out);
}

// Round 7
// 157.880 us; speedup vs baseline: 1.0724x; 1.0724x over previous
//
#include <hip/hip_runtime.h>

#define B 4
#define C 256
#define CQ 32
#define NN 13824   // 24^3
#define MM 1728    // 12^3
#define MS 12

typedef __attribute__((ext_vector_type(8))) short short8;    // 8 bf16 = 4 VGPRs
typedef __attribute__((ext_vector_type(4))) float float4_;   // 16x16 MFMA C/D
typedef __attribute__((ext_vector_type(16))) float floatx16; // 32x32 MFMA C/D

static __device__ inline unsigned rne_bf16(float x) {
  unsigned u = __float_as_uint(x);
  u += 0x7FFFu + ((u >> 16) & 1u);   // round-to-nearest-even bf16
  return u >> 16;
}

// HW packed fp32->bf16 (RNE, bit-identical to rne_bf16 pair). 1 instr vs ~6.
static __device__ inline unsigned cvtpk(float lo, float hi) {
  unsigned r;
  asm("v_cvt_pk_bf16_f32 %0, %1, %2" : "=v"(r) : "v"(lo), "v"(hi));
  return r;
}

#define LOG2E 1.4426950408889634f
#define EXPOFS 43.28085122666891f   // 30 * log2(e)

// ---------------------------------------------------------------------------
// K0: pack Wf/Wg/Wh -> bf16 W16c (A-fragment order for proj_mfma), and
//     Wv (fp32 [256][32]) -> double-bf16 pair Whv/Wlv (hi + residual-lo).
// (r12: restored — r11's per-block W recompute cost ~7us chip-wide.)
// ---------------------------------------------------------------------------
__global__ __launch_bounds__(256) void wcvt_kernel(
    const float* __restrict__ Wf, const float* __restrict__ Wg,
    const float* __restrict__ Wh, const float* __restrict__ Wv,
    unsigned short* __restrict__ W16c, unsigned short* __restrict__ Whv,
    unsigned short* __restrict__ Wlv) {
  const int i = blockIdx.x * 256 + threadIdx.x;   // [0, 32768)
  if (i < 24576) {
    const int kk = i & 7;
    const int rest = i >> 3;
    const int m = rest % 96;
    const int r = rest / 96;
    const int kq = r & 3;
    const int ch = r >> 2;
    const int k = ch * 32 + kq * 8 + kk;
    const float* Wr = (m < 32) ? (Wf + m * C) : (m < 64) ? (Wg + (m - 32) * C)
                                                         : (Wh + (m - 64) * C);
    W16c[i] = (unsigned short)rne_bf16(Wr[k]);
  } else {
    const int j = i - 24576;            // [0, 8192) = c*32 + q for Wv[256][32]
    const float v = Wv[j];
    const unsigned h = rne_bf16(v);
    Whv[j] = (unsigned short)h;
    Wlv[j] = (unsigned short)rne_bf16(v - __uint_as_float(h << 16));
  }
}

// ---------------------------------------------------------------------------
// K1: projections as MFMA GEMM.  [96,256] x [256, NN] per batch.
// r12 = r10 exactly (432 blocks x 256 thr; r11's 128-thr variant doubled the
// chip-wide W staging and regressed).
// ---------------------------------------------------------------------------
#define LOADX(SET, CH)                                                        \
  do {                                                                        \
    const float* xp = xbase4 + (size_t)((CH)*32 + kg * 4) * NN;               \
    _Pragma("unroll") for (int j = 0; j < 4; ++j)                             \
        vx4[SET][j] = *reinterpret_cast<const float4*>(xp + (size_t)j * NN);  \
  } while (0)

#define PACKX(SET, BUF)                                                       \
  do {                                                                        \
    _Pragma("unroll") for (int i = 0; i < 4; ++i) {                           \
      *reinterpret_cast<uint2*>(&xls[BUF][kg >> 1][nq * 4 + i][(kg & 1) * 4]) = \
          make_uint2(cvtpk(vx4[SET][0][i], vx4[SET][1][i]),                   \
                     cvtpk(vx4[SET][2][i], vx4[SET][3][i]));                  \
    }                                                                         \
  } while (0)

#define LOADW(CH)                                                             \
  do {                                                                        \
    const uint4* src = reinterpret_cast<const uint4*>(W16c + (size_t)(CH)*3072); \
    wr0 = src[t];                                                             \
    if (t < 128) wr1 = src[256 + t];                                          \
  } while (0)

#define STOREW(BUF)                                                           \
  do {                                                                        \
    uint4* dst = reinterpret_cast<uint4*>(&wls[BUF][0][0][0]);                \
    dst[t] = wr0;                                                             \
    if (t < 128) dst[256 + t] = wr1;                                          \
  } while (0)

#define COMPUTE(BUF)                                                          \
  do {                                                                        \
    _Pragma("unroll") for (int ks = 0; ks < 2; ++ks) {                        \
      const int kq = ks * 2 + hi;                                             \
      const short8 bfr =                                                      \
          *reinterpret_cast<const short8*>(&xls[BUF][kq][w * 32 + col][0]);   \
      const short8 a0 = *reinterpret_cast<const short8*>(&wls[BUF][kq][col][0]);      \
      const short8 a1 = *reinterpret_cast<const short8*>(&wls[BUF][kq][32 + col][0]); \
      const short8 a2 = *reinterpret_cast<const short8*>(&wls[BUF][kq][64 + col][0]); \
      accf = __builtin_amdgcn_mfma_f32_32x32x16_bf16(a0, bfr, accf, 0, 0, 0); \
      accg = __builtin_amdgcn_mfma_f32_32x32x16_bf16(a1, bfr, accg, 0, 0, 0); \
      acch = __builtin_amdgcn_mfma_f32_32x32x16_bf16(a2, bfr, acch, 0, 0, 0); \
    }                                                                         \
  } while (0)

__global__ __launch_bounds__(256) void proj_mfma(
    const float* __restrict__ x, const unsigned short* __restrict__ W16c,
    unsigned short* __restrict__ f16, unsigned short* __restrict__ g16,
    unsigned short* __restrict__ h16) {
  __shared__ __align__(16) unsigned short xls[2][4][128][8];  // 16 KB
  __shared__ __align__(16) unsigned short wls[2][4][96][8];   // 12 KB
  const int blk = blockIdx.x;
  const int b = blk / 108;
  const int n0 = (blk - b * 108) * 128;
  const int t = threadIdx.x;
  const int w = t >> 6, lane = t & 63;
  const int col = lane & 31, hi = lane >> 5;
  const int nq = t & 31, kg = t >> 5;             // staging: n-quad, k-quad

  floatx16 accf = {0}, accg = {0}, acch = {0};
  const float* xbase4 = x + ((size_t)b * C) * NN + n0 + nq * 4;
  float4 vx4[3][4];         // 3 in-flight register chunk sets (static idx)
  uint4 wr0, wr1;

  // prologue: issue chunks 0,1,2 + W0; pack chunk0 -> LDS[0]
  LOADX(0, 0);
  LOADX(1, 1);
  LOADX(2, 2);
  LOADW(0);
  PACKX(0, 0);
  STOREW(0);
  __syncthreads();

#pragma unroll
  for (int ch = 0; ch < 8; ++ch) {
    const int buf = ch & 1;
    if (ch + 1 < 8) LOADW(ch + 1);                // W next chunk -> regs
    if (ch + 3 < 8) LOADX((ch + 3) % 3, ch + 3);  // x chunk+3 -> ring set
    COMPUTE(buf);
    if (ch + 1 < 8) {                             // write-late: ch+1 -> LDS
      PACKX((ch + 1) % 3, buf ^ 1);
      STOREW(buf ^ 1);
      __syncthreads();
    }
  }

  // ---- epilogue. D layout: col=lane&31 (x n-index), row=(r&3)+8*(r>>2)+4*hi.
  const int n = n0 + w * 32 + col;
  {  // f: bf16 [b][n][c], pack row-pairs -> 8 dword stores
    unsigned short* fp = f16 + ((size_t)b * NN + n) * 32 + hi * 4;
#pragma unroll
    for (int rp = 0; rp < 8; ++rp) {
      const int m = (rp & 1) * 2 + 8 * (rp >> 1);   // 0,2,8,10,16,18,24,26
      *reinterpret_cast<unsigned*>(fp + m) = cvtpk(accf[rp * 2], accf[rp * 2 + 1]);
    }
  }
  unsigned short* gp = g16 + (size_t)b * CQ * NN + n;
  unsigned short* hp = h16 + (size_t)b * CQ * NN + n;
#pragma unroll
  for (int r = 0; r < 16; ++r) {
    const int c = (r & 3) + 8 * (r >> 2) + 4 * hi;
    gp[(size_t)c * NN] = (unsigned short)rne_bf16(accg[r]);
    hp[(size_t)c * NN] = (unsigned short)rne_bf16(acch[r]);
  }
}

// ---------------------------------------------------------------------------
// K2: 2x2x2 maxpool, bf16 in -> bf16 out. (r9, coalesced m-fastest)
// ---------------------------------------------------------------------------
__global__ __launch_bounds__(256) void pool_kernel(
    const unsigned short* __restrict__ g16, const unsigned short* __restrict__ h16,
    unsigned short* __restrict__ gt16, unsigned short* __restrict__ ht16) {
  int i = blockIdx.x * 256 + threadIdx.x;            // [0, B*CQ*MM)
  const int m = i % MM;
  const int rest = i / MM;
  const int c = rest & 31;
  const int b = rest >> 5;
  const int wq = m % MS;
  const int hq = (m / MS) % MS;
  const int dq = m / (MS * MS);
  const size_t base = ((size_t)b * CQ + c) * NN +
                      (2 * dq) * 576 + (2 * hq) * 24 + (2 * wq);
  auto mx2 = [](unsigned u) {
    return fmaxf(__uint_as_float(u << 16), __uint_as_float(u & 0xFFFF0000u));
  };
  const unsigned short* pg = g16 + base;
  const unsigned short* ph = h16 + base;
  float vg = fmaxf(fmaxf(mx2(*(const unsigned*)(pg)),
                         mx2(*(const unsigned*)(pg + 24))),
                   fmaxf(mx2(*(const unsigned*)(pg + 576)),
                         mx2(*(const unsigned*)(pg + 600))));
  float vh = fmaxf(fmaxf(mx2(*(const unsigned*)(ph)),
                         mx2(*(const unsigned*)(ph + 24))),
                   fmaxf(mx2(*(const unsigned*)(ph + 576)),
                         mx2(*(const unsigned*)(ph + 600))));
  gt16[((size_t)b * MM + m) * 32 + c] = (unsigned short)(__float_as_uint(vg) >> 16);
  ht16[((size_t)b * 32 + c) * MM + m] = (unsigned short)(__float_as_uint(vh) >> 16);
}

// ---------------------------------------------------------------------------
// K3: MFMA flash attention + MFMA out-projection/residual.
// r12 = r10 structure (verified 54.7us) with the 27-chunk loop unrolled x2:
// all double-buffer pointers are compile-time constants (no per-iter cndmask
// address selects), the 13 double-iterations carry no conditionals (prefetch
// is unconditional through chunk 26), tail chunk handled separately.
// Arithmetic identical to r10.
// ---------------------------------------------------------------------------
#define ATTN_STEP(GCUR, HCUR, GNB, HNB, K0N, PREF)                            \
  do {                                                                        \
    uint4 gnx, hnx;                                                           \
    if (PREF) {                                                               \
      gnx = *reinterpret_cast<const uint4*>(gsrc + (size_t)((K0N) + gk) * 32 + gseg * 8); \
      hnx = *reinterpret_cast<const uint4*>(hsrc + (size_t)hc * MM + (K0N) + hseg * 8);   \
    }                                                                         \
    float4_ sc[4];                                                            \
    __builtin_amdgcn_s_setprio(1);                                            \
    _Pragma("unroll") for (int T = 0; T < 4; ++T) {                           \
      const short8 gA =                                                       \
          *reinterpret_cast<const short8*>(GCUR + (T * 16 + col) * 40 + Q * 8); \
      float4_ z = {0.f, 0.f, 0.f, 0.f};                                       \
      sc[T] = __builtin_amdgcn_mfma_f32_16x16x32_bf16(gA, fB, z, 0, 0, 0);    \
    }                                                                         \
    __builtin_amdgcn_s_setprio(0);                                            \
    _Pragma("unroll") for (int T = 0; T < 4; ++T) {                           \
      const float p0 = exp2f(fmaf(sc[T][0], LOG2E, -EXPOFS));                 \
      const float p1 = exp2f(fmaf(sc[T][1], LOG2E, -EXPOFS));                 \
      const float p2 = exp2f(fmaf(sc[T][2], LOG2E, -EXPOFS));                 \
      const float p3 = exp2f(fmaf(sc[T][3], LOG2E, -EXPOFS));                 \
      l0 += p0 + p1;                                                          \
      l1 += p2 + p3;                                                          \
      unsigned short* pw = Pls + col * 72 + T * 16 + Q * 4;                   \
      *reinterpret_cast<uint2*>(pw) = make_uint2(cvtpk(p0, p1), cvtpk(p2, p3)); \
    }                                                                         \
    _Pragma("unroll") for (int ks = 0; ks < 2; ++ks) {                        \
      const short8 pA =                                                       \
          *reinterpret_cast<const short8*>(Pls + col * 72 + ks * 32 + Q * 8); \
      const short8 hB0 =                                                      \
          *reinterpret_cast<const short8*>(HCUR + col * 72 + ks * 32 + Q * 8); \
      const short8 hB1 =                                                      \
          *reinterpret_cast<const short8*>(HCUR + (16 + col) * 72 + ks * 32 + Q * 8); \
      __builtin_amdgcn_s_setprio(1);                                          \
      acc0 = __builtin_amdgcn_mfma_f32_16x16x32_bf16(pA, hB0, acc0, 0, 0, 0); \
      acc1 = __builtin_amdgcn_mfma_f32_16x16x32_bf16(pA, hB1, acc1, 0, 0, 0); \
      __builtin_amdgcn_s_setprio(0);                                          \
    }                                                                         \
    if (PREF) {                                                               \
      *reinterpret_cast<uint4*>(GNB + gk * 40 + gseg * 8) = gnx;              \
      *reinterpret_cast<uint4*>(HNB + hc * 72 + hseg * 8) = hnx;              \
    }                                                                         \
    __syncthreads();                                                          \
  } while (0)

__global__ __launch_bounds__(256, 4) void attn_kernel(
    const unsigned short* __restrict__ f16, const unsigned short* __restrict__ gt,
    const unsigned short* __restrict__ ht, const float* __restrict__ x,
    const unsigned short* __restrict__ Whv, const unsigned short* __restrict__ Wlv,
    const float* __restrict__ gamma, float* __restrict__ out) {
  __shared__ __align__(16) unsigned short sm[16896];
  const int blk = blockIdx.x;               // 864
  const int b = blk / 216;
  const int n0 = (blk - b * 216) * 64;
  const int t = threadIdx.x;
  const int w = t >> 6, L = t & 63, Q = L >> 4, col = L & 15;

  unsigned short* fls = sm;
  unsigned short* g0 = sm + 2560;
  unsigned short* g1 = sm + 5120;
  unsigned short* h0 = sm + 7680;
  unsigned short* h1 = sm + 9984;
  unsigned short* Pls = sm + 12288 + w * 1152;

  {
    const unsigned short* fsrc = f16 + ((size_t)(b * NN + n0)) * 32;
    *reinterpret_cast<uint4*>(fls + (t >> 2) * 40 + (t & 3) * 8) =
        *reinterpret_cast<const uint4*>(fsrc + t * 8);
  }
  const unsigned short* gsrc = gt + (size_t)b * MM * 32;
  const unsigned short* hsrc = ht + (size_t)b * 32 * MM;
  const int gk = t >> 2, gseg = t & 3;
  const int hc = t >> 3, hseg = t & 7;
  *reinterpret_cast<uint4*>(g0 + gk * 40 + gseg * 8) =
      *reinterpret_cast<const uint4*>(gsrc + gk * 32 + gseg * 8);
  *reinterpret_cast<uint4*>(h0 + hc * 72 + hseg * 8) =
      *reinterpret_cast<const uint4*>(hsrc + (size_t)hc * MM + hseg * 8);
  __syncthreads();

  const short8 fB = *reinterpret_cast<const short8*>(fls + (w * 16 + col) * 40 + Q * 8);

  float4_ acc0 = {0.f, 0.f, 0.f, 0.f}, acc1 = {0.f, 0.f, 0.f, 0.f};
  float l0 = 0.f, l1 = 0.f;

#pragma unroll 1
  for (int cc = 0; cc < 13; ++cc) {
    const int kn = cc * 128;
    ATTN_STEP(g0, h0, g1, h1, kn + 64, 1);     // chunk 2cc   (prefetch 2cc+1)
    ATTN_STEP(g1, h1, g0, h0, kn + 128, 1);    // chunk 2cc+1 (prefetch 2cc+2)
  }
  ATTN_STEP(g0, h0, g0, h0, 0, 0);             // chunk 26, no prefetch

  // ---- softmax denominator + park o in LDS (stride 33: conflict-free).
  float l = l0 + l1;
  l += __shfl_xor(l, 16);
  l += __shfl_xor(l, 32);
  float* ols = reinterpret_cast<float*>(sm);   // [64][33] fp32 = 8448 B
#pragma unroll
  for (int r = 0; r < 4; ++r) {
    const float linv = 1.f / __shfl(l, Q * 4 + r);
    const int nl = w * 16 + Q * 4 + r;
    ols[nl * 33 + col] = acc0[r] * linv;
    ols[nl * 33 + 16 + col] = acc1[r] * linv;
  }
  __syncthreads();

  // ---- MFMA out-projection: D[256 c][64 n] = (Whv+Wlv) @ o^T, + gamma/x.
  const int colA = L & 31, hiA = L >> 5;
  const float gm = gamma[0];
  short8 Bf[2][2];
#pragma unroll
  for (int nt = 0; nt < 2; ++nt) {
#pragma unroll
    for (int ks = 0; ks < 2; ++ks) {
      const float* p = &ols[(nt * 32 + colA) * 33 + ks * 16 + hiA * 8];
      uint4 uu;
      uu.x = cvtpk(p[0], p[1]);
      uu.y = cvtpk(p[2], p[3]);
      uu.z = cvtpk(p[4], p[5]);
      uu.w = cvtpk(p[6], p[7]);
      Bf[nt][ks] = *reinterpret_cast<short8*>(&uu);
    }
  }
#pragma unroll
  for (int tt = 0; tt < 2; ++tt) {
    const int ct = w + tt * 4;                   // c-tile 0..7
    const int ca = ct * 32 + colA;               // A row = out channel
    const short8 Ah0 = *reinterpret_cast<const short8*>(Whv + ca * 32 + hiA * 8);
    const short8 Ah1 = *reinterpret_cast<const short8*>(Whv + ca * 32 + 16 + hiA * 8);
    const short8 Al0 = *reinterpret_cast<const short8*>(Wlv + ca * 32 + hiA * 8);
    const short8 Al1 = *reinterpret_cast<const short8*>(Wlv + ca * 32 + 16 + hiA * 8);
    floatx16 ac0 = {0}, ac1 = {0};
    __builtin_amdgcn_s_setprio(1);
    ac0 = __builtin_amdgcn_mfma_f32_32x32x16_bf16(Ah0, Bf[0][0], ac0, 0, 0, 0);
    ac0 = __builtin_amdgcn_mfma_f32_32x32x16_bf16(Ah1, Bf[0][1], ac0, 0, 0, 0);
    ac0 = __builtin_amdgcn_mfma_f32_32x32x16_bf16(Al0, Bf[0][0], ac0, 0, 0, 0);
    ac0 = __builtin_amdgcn_mfma_f32_32x32x16_bf16(Al1, Bf[0][1], ac0, 0, 0, 0);
    ac1 = __builtin_amdgcn_mfma_f32_32x32x16_bf16(Ah0, Bf[1][0], ac1, 0, 0, 0);
    ac1 = __builtin_amdgcn_mfma_f32_32x32x16_bf16(Ah1, Bf[1][1], ac1, 0, 0, 0);
    ac1 = __builtin_amdgcn_mfma_f32_32x32x16_bf16(Al0, Bf[1][0], ac1, 0, 0, 0);
    ac1 = __builtin_amdgcn_mfma_f32_32x32x16_bf16(Al1, Bf[1][1], ac1, 0, 0, 0);
    __builtin_amdgcn_s_setprio(0);
#pragma unroll
    for (int nt = 0; nt < 2; ++nt) {
      const floatx16 av = nt ? ac1 : ac0;
      const int n = n0 + nt * 32 + colA;
      const float* xp = x + ((size_t)b * C + ct * 32 + 4 * hiA) * NN + n;
      float* op = out + ((size_t)b * C + ct * 32 + 4 * hiA) * NN + n;
      float xv[16];
#pragma unroll
      for (int r = 0; r < 16; ++r)
        xv[r] = xp[(size_t)((r & 3) + 8 * (r >> 2)) * NN];
#pragma unroll
      for (int r = 0; r < 16; ++r)
        op[(size_t)((r & 3) + 8 * (r >> 2)) * NN] = gm * av[r] + xv[r];
    }
  }
}

// ---------------------------------------------------------------------------
// Workspace layout (float units):
//   f16  @ 0        (884736 fl = [b][n][32] bf16)
//   g16  @ 884736   (884736 fl = [b][c][n] bf16)
//   h16  @ 1769472  (884736)
//   Whv  @ 2654208  (4096 fl = 8192 bf16)
//   Wlv  @ 2658304  (4096 fl = 8192 bf16)
//   gt16 @ 4423680  (110592 fl = [b][m][c] bf16)
//   ht16 @ 4534272  (110592 fl = [b][c][m] bf16)
//   W16c @ 4644864  (12288 fl = 24576 bf16)
// ---------------------------------------------------------------------------
extern "C" void kernel_launch(void* const* d_in, const int* in_sizes, int n_in,
                              void* d_out, int out_size, void* d_ws, size_t ws_size,
                              hipStream_t stream) {
  const float* x     = (const float*)d_in[0];
  const float* Wf    = (const float*)d_in[1];
  const float* Wg    = (const float*)d_in[2];
  const float* Wh    = (const float*)d_in[3];
  const float* Wv    = (const float*)d_in[4];
  const float* gamma = (const float*)d_in[5];
  float* out = (float*)d_out;
  float* ws = (float*)d_ws;

  unsigned short* f16  = (unsigned short*)ws;
  unsigned short* g16  = (unsigned short*)(ws + 884736);
  unsigned short* h16  = (unsigned short*)(ws + 1769472);
  unsigned short* Whv  = (unsigned short*)(ws + 2654208);
  unsigned short* Wlv  = (unsigned short*)(ws + 2658304);
  unsigned short* gt16 = (unsigned short*)(ws + 4423680);
  unsigned short* ht16 = (unsigned short*)(ws + 4534272);
  unsigned short* W16c = (unsigned short*)(ws + 4644864);

  wcvt_kernel<<<128, 256, 0, stream>>>(Wf, Wg, Wh, Wv, W16c, Whv, Wlv);
  proj_mfma<<<B * 108, 256, 0, stream>>>(x, W16c, f16, g16, h16);
  pool_kernel<<<(B * CQ * MM) / 256, 256, 0, stream>>>(g16, h16, gt16, ht16);
  attn_kernel<<<B * (NN / 64), 256, 0, stream>>>(f16, gt16, ht16, x, Whv, Wlv,
                                                 gamma, out);
}